// Round 14
// baseline (400.080 us; speedup 1.0000x reference)
//
#include <hip/hip_runtime.h>
#include <hip/hip_bf16.h>

// Problem constants
#define NROWS 16384      // B*C = 32*512
#define DDIM  256        // H*W
#define KEMB  8192
#define DECAYF 0.99f
#define ONE_MINUS_DECAY 0.01f
#define EPSF 1e-5f
#define CAP  64          // bucket capacity per code; overflow -> direct atomics

// Output layout (all float32, concatenated in return order)
#define O_QST   0
#define O_LOSS  4194304
#define O_IDX   4194305
#define O_EMB   4210689
#define O_ECS   6307841
#define O_EES   6316033

typedef __attribute__((ext_vector_type(8))) short short8;
typedef __attribute__((ext_vector_type(4))) float f32x4;

// fp32 -> bf16 (RNE) as raw ushort, and back
static __device__ __forceinline__ unsigned short f2bf(float x) {
    unsigned int u = __float_as_uint(x);
    return (unsigned short)((u + 0x7fffu + ((u >> 16) & 1u)) >> 16);
}
static __device__ __forceinline__ float bf2f(unsigned short h) {
    return __uint_as_float(((unsigned int)h) << 16);
}

// async global->LDS, 16B per lane; lds base wave-uniform, lane i lands at +16*i
static __device__ __forceinline__ void gload16(const unsigned short* g, unsigned short* l) {
    __builtin_amdgcn_global_load_lds(
        (const __attribute__((address_space(1))) unsigned int*)g,
        (__attribute__((address_space(3))) unsigned int*)l, 16, 0, 0);
}

// ---------------- prep_all: fused prep (R10-verified) -----------------------
__global__ __launch_bounds__(256) void prep_all(const float* __restrict__ z,
                                                const float* __restrict__ emb,
                                                const float* __restrict__ ecs_in,
                                                const float* __restrict__ ees_in,
                                                float* __restrict__ enorm,
                                                unsigned short* __restrict__ eh,
                                                unsigned short* __restrict__ el,
                                                unsigned short* __restrict__ zh,
                                                unsigned short* __restrict__ zl,
                                                float* __restrict__ o_ees,
                                                float* __restrict__ part_e,
                                                unsigned int* __restrict__ cnt,
                                                unsigned long long* __restrict__ key64) {
    const int b = blockIdx.x;
    const int w = threadIdx.x >> 6;
    const int lane = threadIdx.x & 63;
    if (b < 2048) {
        const int k = b * 4 + w;
        const int base = k * DDIM + lane * 4;
        const float4 v = *(const float4*)&emb[base];
        ushort4 h, l;
        {
            const float* vp = (const float*)&v;
            unsigned short hh;
            hh = f2bf(vp[0]); h.x = hh; l.x = f2bf(vp[0] - bf2f(hh));
            hh = f2bf(vp[1]); h.y = hh; l.y = f2bf(vp[1] - bf2f(hh));
            hh = f2bf(vp[2]); h.z = hh; l.z = f2bf(vp[2] - bf2f(hh));
            hh = f2bf(vp[3]); h.w = hh; l.w = f2bf(vp[3] - bf2f(hh));
        }
        *(ushort4*)&eh[base] = h;
        *(ushort4*)&el[base] = l;
        const float4 s = *(const float4*)&ees_in[base];
        float4 so;
        so.x = DECAYF * s.x; so.y = DECAYF * s.y; so.z = DECAYF * s.z; so.w = DECAYF * s.w;
        *(float4*)&o_ees[base] = so;
        float sum = v.x * v.x + v.y * v.y + v.z * v.z + v.w * v.w;
        for (int o = 32; o; o >>= 1) sum += __shfl_down(sum, o);
        __shared__ float sc[4];
        if (lane == 0) {
            enorm[k] = sum;
            sc[w] = DECAYF * ecs_in[k];
            cnt[k] = 0u;
        }
        __syncthreads();
        if (threadIdx.x == 0) part_e[b] = sc[0] + sc[1] + sc[2] + sc[3];
    } else {
        const int n = (b - 2048) * 4 + w;
        const int base = n * DDIM + lane * 4;
        const float4 v = *(const float4*)&z[base];
        ushort4 h, l;
        {
            const float* vp = (const float*)&v;
            unsigned short hh;
            hh = f2bf(vp[0]); h.x = hh; l.x = f2bf(vp[0] - bf2f(hh));
            hh = f2bf(vp[1]); h.y = hh; l.y = f2bf(vp[1] - bf2f(hh));
            hh = f2bf(vp[2]); h.z = hh; l.z = f2bf(vp[2] - bf2f(hh));
            hh = f2bf(vp[3]); h.w = hh; l.w = f2bf(vp[3] - bf2f(hh));
        }
        *(ushort4*)&zh[base] = h;
        *(ushort4*)&zl[base] = l;
        if (lane == 0) key64[n] = ~0ull;
    }
}

// ---------------- argmin_mfma (R14): 128x128, 8 waves, dbuf, 2 blocks/CU ----
// Occupancy probe: same stage-early dbuf + chunk-XOR + scalarized staging as
// the 221us R11 kernel, but 128x128 tile -> 64KB LDS -> 2 resident blocks/CU
// (4 waves/SIMD). Mechanism: block A's end-of-step vmcnt drain overlaps with
// block B's MFMA (inter-block version of what R7's intra-block phasing
// couldn't do at 1 block/CU). Bank geometry unchanged (row stride 64B).
// Numerics: per-output MFMA chain order identical to R13.
__global__ __launch_bounds__(512) void argmin_mfma(const unsigned short* __restrict__ zh,
                                                   const unsigned short* __restrict__ zl,
                                                   const unsigned short* __restrict__ eh,
                                                   const unsigned short* __restrict__ el,
                                                   const float* __restrict__ enorm,
                                                   unsigned long long* __restrict__ key64) {
    __shared__ unsigned short Ah[2][128][32];
    __shared__ unsigned short Al[2][128][32];
    __shared__ unsigned short Bh[2][128][32];
    __shared__ unsigned short Bl[2][128][32];

    const int tid = threadIdx.x;
    const int lane = tid & 63;
    const int wid = tid >> 6;          // 0..7
    const int wm = wid >> 2;           // 0..1: row half (64 rows each)
    const int wn = wid & 3;            // 0..3: col quarter (32 cols each)
    const int tx = lane & 15, quad = lane >> 4;

    const int row0 = blockIdx.x * 128;
    const int col0 = blockIdx.y * 128;

    // staging: lane l -> row l>>2 within a 16-row slab, swizzled 16B chunk
    const int r16 = lane >> 2;
    const int gc8 = (((lane & 3) ^ ((lane >> 3) & 3)) * 8);
    // fragment-read swizzle: chunk = quad ^ ((row>>1)&3); row low4 = tx
    const int sw = (quad ^ ((tx >> 1) & 3)) * 8;

    // provably wave-uniform staging config via readfirstlane
    const int uwid = __builtin_amdgcn_readfirstlane(wid);
    const unsigned short* gsrc = (uwid < 2) ? zh : (uwid < 4) ? zl : (uwid < 6) ? eh : el;
    unsigned short* lds0 = (uwid < 2) ? &Ah[0][0][0] : (uwid < 4) ? &Al[0][0][0]
                         : (uwid < 6) ? &Bh[0][0][0] : &Bl[0][0][0];
    const int gbase0 = (uwid < 4) ? row0 : col0;
    const int slab0 = (uwid & 1) * 4;   // 4 slabs of 16 rows per wave

    // scalar base (wave-uniform) + per-lane voff computed once
    const unsigned short* sbase = gsrc + (size_t)gbase0 * DDIM;
    int voff[4];
#pragma unroll
    for (int i = 0; i < 4; i++)
        voff[i] = ((slab0 + i) * 16 + r16) * DDIM + gc8;

    auto stage = [&](int b, int dk) {
        const unsigned short* sb = sbase + dk;               // wave-uniform add
        unsigned short* lb = lds0 + b * 4096 + slab0 * 512;  // wave-uniform
#pragma unroll
        for (int i = 0; i < 4; i++)
            gload16(sb + voff[i], lb + i * 512);
    };

    f32x4 acc[4][2];
#pragma unroll
    for (int i = 0; i < 4; i++)
#pragma unroll
        for (int j = 0; j < 2; j++) acc[i][j] = (f32x4){0.f, 0.f, 0.f, 0.f};

    stage(0, 0);
    __syncthreads();   // buf0 resident

    for (int d8 = 0; d8 < 8; d8++) {
        const int cur = d8 & 1;
        if (d8 < 7) stage(cur ^ 1, (d8 + 1) * 32);   // in flight during MFMA

        short8 bH[2], bL[2];
        const int bbase = wn * 32 + tx;
#pragma unroll
        for (int nj = 0; nj < 2; nj++) {
            bH[nj] = *(const short8*)&Bh[cur][bbase + nj * 16][sw];
            bL[nj] = *(const short8*)&Bl[cur][bbase + nj * 16][sw];
        }
        const int abase = wm * 64 + tx;
#pragma unroll
        for (int mi = 0; mi < 4; mi++) {
            const short8 aH = *(const short8*)&Ah[cur][abase + mi * 16][sw];
            const short8 aL = *(const short8*)&Al[cur][abase + mi * 16][sw];
#pragma unroll
            for (int nj = 0; nj < 2; nj++) {
                acc[mi][nj] = __builtin_amdgcn_mfma_f32_16x16x32_bf16(aH, bH[nj], acc[mi][nj], 0, 0, 0);
                acc[mi][nj] = __builtin_amdgcn_mfma_f32_16x16x32_bf16(aL, bH[nj], acc[mi][nj], 0, 0, 0);
                acc[mi][nj] = __builtin_amdgcn_mfma_f32_16x16x32_bf16(aH, bL[nj], acc[mi][nj], 0, 0, 0);
            }
        }
        __syncthreads();   // all reads of cur done + next buf resident
    }

    // epilogue: dist = ||e||^2 - 2 x.e ; fused argmin, k-ascending tie-break.
    // C/D layout: col = lane&15 (+nj*16), row = quad*4 + reg (+mi*16)
    float en[2];
    int colv[2];
#pragma unroll
    for (int nj = 0; nj < 2; nj++) {
        colv[nj] = col0 + wn * 32 + nj * 16 + tx;
        en[nj] = enorm[colv[nj]];
    }
#pragma unroll
    for (int mi = 0; mi < 4; mi++) {
#pragma unroll
        for (int r = 0; r < 4; r++) {
            unsigned long long best = ~0ull;
#pragma unroll
            for (int nj = 0; nj < 2; nj++) {
                float d = en[nj] - 2.0f * acc[mi][nj][r];
                unsigned int db = __float_as_uint(d);
                db = (db & 0x80000000u) ? ~db : (db | 0x80000000u);
                unsigned long long key = ((unsigned long long)db << 32) | (unsigned int)colv[nj];
                if (key < best) best = key;
            }
#pragma unroll
            for (int m = 1; m < 16; m <<= 1) {
                unsigned long long o = __shfl_xor(best, m);
                if (o < best) best = o;
            }
            if (tx == 0)
                atomicMin(&key64[row0 + wm * 64 + mi * 16 + quad * 4 + r], best);
        }
    }
}

// ---------------- quant_stats: qst + loss + idx + bucket/overflow -----------
// (R10-verified: bucket within CAP; overflow rows atomicAdd 0.01*z to o_ees)
__global__ __launch_bounds__(256) void quant_stats(const float* __restrict__ z,
                                                   const float* __restrict__ emb,
                                                   const unsigned long long* __restrict__ key64,
                                                   float* __restrict__ o_qst,
                                                   float* __restrict__ o_idx,
                                                   unsigned int* __restrict__ cnt,
                                                   unsigned short* __restrict__ bucket,
                                                   float* __restrict__ o_ees,
                                                   float* __restrict__ part_q) {
    const int w = threadIdx.x >> 6;
    const int lane = threadIdx.x & 63;
    const int nbase = blockIdx.x * 16 + w * 4;
    const int d0 = lane * 4;
    float ploc = 0.f;
#pragma unroll
    for (int r = 0; r < 4; r++) {
        const int n = nbase + r;
        const int k = (int)(key64[n] & 0xFFFFFFFFull);
        const float4 zv = *(const float4*)&z[n * DDIM + d0];
        const float4 ev = *(const float4*)&emb[k * DDIM + d0];
        const float dx = ev.x - zv.x, dy = ev.y - zv.y, dz2 = ev.z - zv.z, dw = ev.w - zv.w;
        float4 q;
        q.x = zv.x + dx; q.y = zv.y + dy; q.z = zv.z + dz2; q.w = zv.w + dw;
        *(float4*)&o_qst[n * DDIM + d0] = q;
        ploc += dx * dx + dy * dy + dz2 * dz2 + dw * dw;
        unsigned int pos = 0u;
        if (lane == 0) {
            o_idx[n] = (float)k;
            pos = atomicAdd(&cnt[k], 1u);
        }
        pos = __shfl(pos, 0);
        if (pos < CAP) {
            if (lane == 0) bucket[(size_t)k * CAP + pos] = (unsigned short)n;
        } else {
            atomicAdd(&o_ees[(size_t)k * DDIM + d0 + 0], ONE_MINUS_DECAY * zv.x);
            atomicAdd(&o_ees[(size_t)k * DDIM + d0 + 1], ONE_MINUS_DECAY * zv.y);
            atomicAdd(&o_ees[(size_t)k * DDIM + d0 + 2], ONE_MINUS_DECAY * zv.z);
            atomicAdd(&o_ees[(size_t)k * DDIM + d0 + 3], ONE_MINUS_DECAY * zv.w);
        }
    }
    for (int o = 32; o; o >>= 1) ploc += __shfl_down(ploc, o);
    __shared__ float sh[4];
    if (lane == 0) sh[w] = ploc;
    __syncthreads();
    if (threadIdx.x == 0) part_q[blockIdx.x] = sh[0] + sh[1] + sh[2] + sh[3];
}

// ---------------- finalize: bucket gather + EMA + embedding + ecs + loss ----
// (R10-verified: 454us ovf-scan removed; ushort4-batched gather)
__global__ __launch_bounds__(256) void finalize_kernel(const float* __restrict__ z,
                                                       const float* __restrict__ ecs_in,
                                                       const unsigned int* __restrict__ cnt,
                                                       const unsigned short* __restrict__ bucket,
                                                       const float* __restrict__ part_e,
                                                       const float* __restrict__ part_q,
                                                       float* __restrict__ o_ecs,
                                                       float* __restrict__ o_ees,
                                                       float* __restrict__ o_emb,
                                                       float* __restrict__ o_loss) {
    const int k = blockIdx.x;
    const int d = threadIdx.x;
    __shared__ float red[256];
    float s = 0.f;
    for (int i = d; i < 2048; i += 256) s += part_e[i];
    red[d] = s;
    __syncthreads();
    for (int o = 128; o; o >>= 1) {
        if (d < o) red[d] += red[d + o];
        __syncthreads();
    }
    const float ntot = red[0] + ONE_MINUS_DECAY * (float)NROWS;

    const unsigned int c = cnt[k];
    const int cb = (int)(c < CAP ? c : CAP);
    float ei = 0.f;
    int i = 0;
    for (; i + 4 <= cb; i += 4) {
        const ushort4 b4 = *(const ushort4*)&bucket[(size_t)k * CAP + i];
        ei += z[(size_t)b4.x * DDIM + d];
        ei += z[(size_t)b4.y * DDIM + d];
        ei += z[(size_t)b4.z * DDIM + d];
        ei += z[(size_t)b4.w * DDIM + d];
    }
    for (; i < cb; i++) {
        ei += z[(size_t)bucket[(size_t)k * CAP + i] * DDIM + d];
    }
    const float new_ees = o_ees[(size_t)k * DDIM + d] + ONE_MINUS_DECAY * ei;
    const float new_ecs = DECAYF * ecs_in[k] + ONE_MINUS_DECAY * (float)c;
    const float sm = (new_ecs + EPSF) / (ntot + (float)KEMB * EPSF) * ntot;
    o_ees[(size_t)k * DDIM + d] = new_ees;
    o_emb[(size_t)k * DDIM + d] = new_ees / sm;
    if (d == 0) o_ecs[k] = new_ecs;

    if (k == 0) {
        __syncthreads();
        float s2 = 0.f;
        for (int i2 = d; i2 < 1024; i2 += 256) s2 += part_q[i2];
        red[d] = s2;
        __syncthreads();
        for (int o = 128; o; o >>= 1) {
            if (d < o) red[d] += red[d + o];
            __syncthreads();
        }
        if (d == 0) o_loss[0] = 0.25f * red[0] / (float)(NROWS * DDIM);
    }
}

extern "C" void kernel_launch(void* const* d_in, const int* in_sizes, int n_in,
                              void* d_out, int out_size, void* d_ws, size_t ws_size,
                              hipStream_t stream) {
    const float* z   = (const float*)d_in[0];
    const float* emb = (const float*)d_in[1];
    const float* ecs = (const float*)d_in[2];
    const float* ees = (const float*)d_in[3];

    float* out = (float*)d_out;
    char*  ws  = (char*)d_ws;

    // ws head: enorm 32KB | key64 128KB | part_e 8KB | part_q 4KB | cnt 32KB
    //          | bucket 1MB
    float* enorm = (float*)ws;                                    // 8192 f
    unsigned long long* key64 = (unsigned long long*)(ws + 32768);// 16384 u64
    float* part_e = (float*)(ws + 163840);                        // 2048 f
    float* part_q = part_e + 2048;                                // 1024 f
    unsigned int* cnt = (unsigned int*)(ws + 176128);             // 8192 u32
    unsigned short* bucket = (unsigned short*)(ws + 208896);      // 8192*64 u16

    // bf16 hi/lo scratch: prefer d_ws if large enough, else alias output
    // regions overwritten later (zh/zl in O_QST, eh/el in O_EMB).
    const size_t big0 = 208896 + (size_t)KEMB * CAP * 2;          // 1257472
    const size_t bigbytes = (size_t)(NROWS + KEMB) * DDIM * 2 * 2;// 24 MB
    unsigned short *zh, *zl, *ehp, *elp;
    if (ws_size >= big0 + bigbytes) {
        zh  = (unsigned short*)(ws + big0);
        zl  = zh + NROWS * DDIM;
        ehp = zl + NROWS * DDIM;
        elp = ehp + KEMB * DDIM;
    } else {
        zh  = (unsigned short*)(out + O_QST);
        zl  = zh + NROWS * DDIM;
        ehp = (unsigned short*)(out + O_EMB);
        elp = ehp + KEMB * DDIM;
    }

    prep_all<<<6144, 256, 0, stream>>>(z, emb, ecs, ees, enorm, ehp, elp,
                                       zh, zl, out + O_EES, part_e, cnt, key64);
    argmin_mfma<<<dim3(NROWS / 128, KEMB / 128), 512, 0, stream>>>(zh, zl, ehp, elp, enorm, key64);
    quant_stats<<<NROWS / 16, 256, 0, stream>>>(z, emb, key64, out + O_QST, out + O_IDX,
                                                cnt, bucket, out + O_EES, part_q);
    finalize_kernel<<<KEMB, DDIM, 0, stream>>>(z, ecs, cnt, bucket,
                                               part_e, part_q,
                                               out + O_ECS, out + O_EES,
                                               out + O_EMB, out + O_LOSS);
}

// Round 15
// 332.650 us; speedup vs baseline: 1.2027x; 1.2027x over previous
//
#include <hip/hip_runtime.h>
#include <hip/hip_bf16.h>

// Problem constants
#define NROWS 16384      // B*C = 32*512
#define DDIM  256        // H*W
#define KEMB  8192
#define DECAYF 0.99f
#define ONE_MINUS_DECAY 0.01f
#define EPSF 1e-5f
#define CAP  64          // bucket capacity per code; overflow -> direct atomics

// Output layout (all float32, concatenated in return order)
#define O_QST   0
#define O_LOSS  4194304
#define O_IDX   4194305
#define O_EMB   4210689
#define O_ECS   6307841
#define O_EES   6316033

typedef __attribute__((ext_vector_type(8))) short short8;
typedef __attribute__((ext_vector_type(4))) float f32x4;

// fp32 -> bf16 (RNE) as raw ushort, and back
static __device__ __forceinline__ unsigned short f2bf(float x) {
    unsigned int u = __float_as_uint(x);
    return (unsigned short)((u + 0x7fffu + ((u >> 16) & 1u)) >> 16);
}
static __device__ __forceinline__ float bf2f(unsigned short h) {
    return __uint_as_float(((unsigned int)h) << 16);
}

// async global->LDS, 16B per lane; lds base wave-uniform, lane i lands at +16*i
static __device__ __forceinline__ void gload16(const unsigned short* g, unsigned short* l) {
    __builtin_amdgcn_global_load_lds(
        (const __attribute__((address_space(1))) unsigned int*)g,
        (__attribute__((address_space(3))) unsigned int*)l, 16, 0, 0);
}

// ---------------- prep_all: fused prep (R10-verified) -----------------------
__global__ __launch_bounds__(256) void prep_all(const float* __restrict__ z,
                                                const float* __restrict__ emb,
                                                const float* __restrict__ ecs_in,
                                                const float* __restrict__ ees_in,
                                                float* __restrict__ enorm,
                                                unsigned short* __restrict__ eh,
                                                unsigned short* __restrict__ el,
                                                unsigned short* __restrict__ zh,
                                                unsigned short* __restrict__ zl,
                                                float* __restrict__ o_ees,
                                                float* __restrict__ part_e,
                                                unsigned int* __restrict__ cnt,
                                                unsigned long long* __restrict__ key64) {
    const int b = blockIdx.x;
    const int w = threadIdx.x >> 6;
    const int lane = threadIdx.x & 63;
    if (b < 2048) {
        const int k = b * 4 + w;
        const int base = k * DDIM + lane * 4;
        const float4 v = *(const float4*)&emb[base];
        ushort4 h, l;
        {
            const float* vp = (const float*)&v;
            unsigned short hh;
            hh = f2bf(vp[0]); h.x = hh; l.x = f2bf(vp[0] - bf2f(hh));
            hh = f2bf(vp[1]); h.y = hh; l.y = f2bf(vp[1] - bf2f(hh));
            hh = f2bf(vp[2]); h.z = hh; l.z = f2bf(vp[2] - bf2f(hh));
            hh = f2bf(vp[3]); h.w = hh; l.w = f2bf(vp[3] - bf2f(hh));
        }
        *(ushort4*)&eh[base] = h;
        *(ushort4*)&el[base] = l;
        const float4 s = *(const float4*)&ees_in[base];
        float4 so;
        so.x = DECAYF * s.x; so.y = DECAYF * s.y; so.z = DECAYF * s.z; so.w = DECAYF * s.w;
        *(float4*)&o_ees[base] = so;
        float sum = v.x * v.x + v.y * v.y + v.z * v.z + v.w * v.w;
        for (int o = 32; o; o >>= 1) sum += __shfl_down(sum, o);
        __shared__ float sc[4];
        if (lane == 0) {
            enorm[k] = sum;
            sc[w] = DECAYF * ecs_in[k];
            cnt[k] = 0u;
        }
        __syncthreads();
        if (threadIdx.x == 0) part_e[b] = sc[0] + sc[1] + sc[2] + sc[3];
    } else {
        const int n = (b - 2048) * 4 + w;
        const int base = n * DDIM + lane * 4;
        const float4 v = *(const float4*)&z[base];
        ushort4 h, l;
        {
            const float* vp = (const float*)&v;
            unsigned short hh;
            hh = f2bf(vp[0]); h.x = hh; l.x = f2bf(vp[0] - bf2f(hh));
            hh = f2bf(vp[1]); h.y = hh; l.y = f2bf(vp[1] - bf2f(hh));
            hh = f2bf(vp[2]); h.z = hh; l.z = f2bf(vp[2] - bf2f(hh));
            hh = f2bf(vp[3]); h.w = hh; l.w = f2bf(vp[3] - bf2f(hh));
        }
        *(ushort4*)&zh[base] = h;
        *(ushort4*)&zl[base] = l;
        if (lane == 0) key64[n] = ~0ull;
    }
}

// ---------------- argmin_mfma (R11/R13-verified, 220us) ---------------------
// 256x256, 8 waves, dbuf LDS, bf16x3 16x16x32 MFMA + fused argmin.
// Verified: chunk-XOR swizzle both-sides (R2: conflicts 1.7e7->0), 256^2
// dbuf stage-before-compute (R6: 294->230), readfirstlane-scalarized
// staging (R11: 231->221, VGPR 124->108).
// Rejected with mechanism: XCD supertile (R4: L3-fit, FETCH 95->41MB but
// +2us); 8-phase intra-block (R7: barrier overhead > drain saved at 2
// waves/SIMD); 32x32x16 shape (R12: 64B row stride = 2 bank-base classes ->
// unavoidable >=4-way conflict with linear gload_lds); 128^2 @ 2 blocks/CU
// (R14: occupancy 22->42% but intensity halved, 220->270us).
__global__ __launch_bounds__(512) void argmin_mfma(const unsigned short* __restrict__ zh,
                                                   const unsigned short* __restrict__ zl,
                                                   const unsigned short* __restrict__ eh,
                                                   const unsigned short* __restrict__ el,
                                                   const float* __restrict__ enorm,
                                                   unsigned long long* __restrict__ key64) {
    __shared__ unsigned short Ah[2][256][32];
    __shared__ unsigned short Al[2][256][32];
    __shared__ unsigned short Bh[2][256][32];
    __shared__ unsigned short Bl[2][256][32];

    const int tid = threadIdx.x;
    const int lane = tid & 63;
    const int wid = tid >> 6;          // 0..7
    const int wm = wid >> 2;           // 0..1: row half (128 rows)
    const int wn = wid & 3;            // 0..3: col quarter (64 cols)
    const int tx = lane & 15, quad = lane >> 4;

    const int row0 = blockIdx.x * 256;
    const int col0 = blockIdx.y * 256;

    // staging: lane l -> row l>>2 within a 16-row slab, swizzled 16B chunk
    const int r16 = lane >> 2;
    const int gc8 = (((lane & 3) ^ ((lane >> 3) & 3)) * 8);
    // fragment-read swizzle: chunk = quad ^ ((row>>1)&3); row low4 = tx
    const int sw = (quad ^ ((tx >> 1) & 3)) * 8;

    // provably wave-uniform staging config via readfirstlane
    const int uwid = __builtin_amdgcn_readfirstlane(wid);
    const unsigned short* gsrc = (uwid < 2) ? zh : (uwid < 4) ? zl : (uwid < 6) ? eh : el;
    unsigned short* lds0 = (uwid < 2) ? &Ah[0][0][0] : (uwid < 4) ? &Al[0][0][0]
                         : (uwid < 6) ? &Bh[0][0][0] : &Bl[0][0][0];
    const int gbase0 = (uwid < 4) ? row0 : col0;
    const int slab0 = (uwid & 1) * 8;

    // scalar base (wave-uniform) + per-lane voff computed once
    const unsigned short* sbase = gsrc + (size_t)gbase0 * DDIM;
    int voff[8];
#pragma unroll
    for (int i = 0; i < 8; i++)
        voff[i] = ((slab0 + i) * 16 + r16) * DDIM + gc8;

    auto stage = [&](int b, int dk) {
        const unsigned short* sb = sbase + dk;          // wave-uniform add
        unsigned short* lb = lds0 + b * 8192 + slab0 * 512;  // wave-uniform
#pragma unroll
        for (int i = 0; i < 8; i++)
            gload16(sb + voff[i], lb + i * 512);
    };

    f32x4 acc[8][4];
#pragma unroll
    for (int i = 0; i < 8; i++)
#pragma unroll
        for (int j = 0; j < 4; j++) acc[i][j] = (f32x4){0.f, 0.f, 0.f, 0.f};

    stage(0, 0);
    __syncthreads();   // buf0 resident

    for (int d8 = 0; d8 < 8; d8++) {
        const int cur = d8 & 1;
        if (d8 < 7) stage(cur ^ 1, (d8 + 1) * 32);   // in flight during MFMA

        short8 bH[4], bL[4];
        const int bbase = wn * 64 + tx;
#pragma unroll
        for (int nj = 0; nj < 4; nj++) {
            bH[nj] = *(const short8*)&Bh[cur][bbase + nj * 16][sw];
            bL[nj] = *(const short8*)&Bl[cur][bbase + nj * 16][sw];
        }
        const int abase = wm * 128 + tx;
#pragma unroll
        for (int mi = 0; mi < 8; mi++) {
            const short8 aH = *(const short8*)&Ah[cur][abase + mi * 16][sw];
            const short8 aL = *(const short8*)&Al[cur][abase + mi * 16][sw];
#pragma unroll
            for (int nj = 0; nj < 4; nj++) {
                acc[mi][nj] = __builtin_amdgcn_mfma_f32_16x16x32_bf16(aH, bH[nj], acc[mi][nj], 0, 0, 0);
                acc[mi][nj] = __builtin_amdgcn_mfma_f32_16x16x32_bf16(aL, bH[nj], acc[mi][nj], 0, 0, 0);
                acc[mi][nj] = __builtin_amdgcn_mfma_f32_16x16x32_bf16(aH, bL[nj], acc[mi][nj], 0, 0, 0);
            }
        }
        __syncthreads();   // all reads of cur done + next buf resident
    }

    // epilogue: dist = ||e||^2 - 2 x.e ; fused argmin, k-ascending tie-break.
    // C/D layout: col = lane&15 (+nj*16), row = quad*4 + reg (+mi*16)
    float en[4];
    int colv[4];
#pragma unroll
    for (int nj = 0; nj < 4; nj++) {
        colv[nj] = col0 + wn * 64 + nj * 16 + tx;
        en[nj] = enorm[colv[nj]];
    }
#pragma unroll
    for (int mi = 0; mi < 8; mi++) {
#pragma unroll
        for (int r = 0; r < 4; r++) {
            unsigned long long best = ~0ull;
#pragma unroll
            for (int nj = 0; nj < 4; nj++) {
                float d = en[nj] - 2.0f * acc[mi][nj][r];
                unsigned int db = __float_as_uint(d);
                db = (db & 0x80000000u) ? ~db : (db | 0x80000000u);
                unsigned long long key = ((unsigned long long)db << 32) | (unsigned int)colv[nj];
                if (key < best) best = key;
            }
#pragma unroll
            for (int m = 1; m < 16; m <<= 1) {
                unsigned long long o = __shfl_xor(best, m);
                if (o < best) best = o;
            }
            if (tx == 0)
                atomicMin(&key64[row0 + wm * 128 + mi * 16 + quad * 4 + r], best);
        }
    }
}

// ---------------- quant_stats: qst + loss + idx + bucket/overflow -----------
// (R10-verified: bucket within CAP; overflow rows atomicAdd 0.01*z to o_ees)
__global__ __launch_bounds__(256) void quant_stats(const float* __restrict__ z,
                                                   const float* __restrict__ emb,
                                                   const unsigned long long* __restrict__ key64,
                                                   float* __restrict__ o_qst,
                                                   float* __restrict__ o_idx,
                                                   unsigned int* __restrict__ cnt,
                                                   unsigned short* __restrict__ bucket,
                                                   float* __restrict__ o_ees,
                                                   float* __restrict__ part_q) {
    const int w = threadIdx.x >> 6;
    const int lane = threadIdx.x & 63;
    const int nbase = blockIdx.x * 16 + w * 4;
    const int d0 = lane * 4;
    float ploc = 0.f;
#pragma unroll
    for (int r = 0; r < 4; r++) {
        const int n = nbase + r;
        const int k = (int)(key64[n] & 0xFFFFFFFFull);
        const float4 zv = *(const float4*)&z[n * DDIM + d0];
        const float4 ev = *(const float4*)&emb[k * DDIM + d0];
        const float dx = ev.x - zv.x, dy = ev.y - zv.y, dz2 = ev.z - zv.z, dw = ev.w - zv.w;
        float4 q;
        q.x = zv.x + dx; q.y = zv.y + dy; q.z = zv.z + dz2; q.w = zv.w + dw;
        *(float4*)&o_qst[n * DDIM + d0] = q;
        ploc += dx * dx + dy * dy + dz2 * dz2 + dw * dw;
        unsigned int pos = 0u;
        if (lane == 0) {
            o_idx[n] = (float)k;
            pos = atomicAdd(&cnt[k], 1u);
        }
        pos = __shfl(pos, 0);
        if (pos < CAP) {
            if (lane == 0) bucket[(size_t)k * CAP + pos] = (unsigned short)n;
        } else {
            atomicAdd(&o_ees[(size_t)k * DDIM + d0 + 0], ONE_MINUS_DECAY * zv.x);
            atomicAdd(&o_ees[(size_t)k * DDIM + d0 + 1], ONE_MINUS_DECAY * zv.y);
            atomicAdd(&o_ees[(size_t)k * DDIM + d0 + 2], ONE_MINUS_DECAY * zv.z);
            atomicAdd(&o_ees[(size_t)k * DDIM + d0 + 3], ONE_MINUS_DECAY * zv.w);
        }
    }
    for (int o = 32; o; o >>= 1) ploc += __shfl_down(ploc, o);
    __shared__ float sh[4];
    if (lane == 0) sh[w] = ploc;
    __syncthreads();
    if (threadIdx.x == 0) part_q[blockIdx.x] = sh[0] + sh[1] + sh[2] + sh[3];
}

// ---------------- finalize: bucket gather + EMA + embedding + ecs + loss ----
// (R10-verified: 454us ovf-scan removed; ushort4-batched gather)
__global__ __launch_bounds__(256) void finalize_kernel(const float* __restrict__ z,
                                                       const float* __restrict__ ecs_in,
                                                       const unsigned int* __restrict__ cnt,
                                                       const unsigned short* __restrict__ bucket,
                                                       const float* __restrict__ part_e,
                                                       const float* __restrict__ part_q,
                                                       float* __restrict__ o_ecs,
                                                       float* __restrict__ o_ees,
                                                       float* __restrict__ o_emb,
                                                       float* __restrict__ o_loss) {
    const int k = blockIdx.x;
    const int d = threadIdx.x;
    __shared__ float red[256];
    float s = 0.f;
    for (int i = d; i < 2048; i += 256) s += part_e[i];
    red[d] = s;
    __syncthreads();
    for (int o = 128; o; o >>= 1) {
        if (d < o) red[d] += red[d + o];
        __syncthreads();
    }
    const float ntot = red[0] + ONE_MINUS_DECAY * (float)NROWS;

    const unsigned int c = cnt[k];
    const int cb = (int)(c < CAP ? c : CAP);
    float ei = 0.f;
    int i = 0;
    for (; i + 4 <= cb; i += 4) {
        const ushort4 b4 = *(const ushort4*)&bucket[(size_t)k * CAP + i];
        ei += z[(size_t)b4.x * DDIM + d];
        ei += z[(size_t)b4.y * DDIM + d];
        ei += z[(size_t)b4.z * DDIM + d];
        ei += z[(size_t)b4.w * DDIM + d];
    }
    for (; i < cb; i++) {
        ei += z[(size_t)bucket[(size_t)k * CAP + i] * DDIM + d];
    }
    const float new_ees = o_ees[(size_t)k * DDIM + d] + ONE_MINUS_DECAY * ei;
    const float new_ecs = DECAYF * ecs_in[k] + ONE_MINUS_DECAY * (float)c;
    const float sm = (new_ecs + EPSF) / (ntot + (float)KEMB * EPSF) * ntot;
    o_ees[(size_t)k * DDIM + d] = new_ees;
    o_emb[(size_t)k * DDIM + d] = new_ees / sm;
    if (d == 0) o_ecs[k] = new_ecs;

    if (k == 0) {
        __syncthreads();
        float s2 = 0.f;
        for (int i2 = d; i2 < 1024; i2 += 256) s2 += part_q[i2];
        red[d] = s2;
        __syncthreads();
        for (int o = 128; o; o >>= 1) {
            if (d < o) red[d] += red[d + o];
            __syncthreads();
        }
        if (d == 0) o_loss[0] = 0.25f * red[0] / (float)(NROWS * DDIM);
    }
}

extern "C" void kernel_launch(void* const* d_in, const int* in_sizes, int n_in,
                              void* d_out, int out_size, void* d_ws, size_t ws_size,
                              hipStream_t stream) {
    const float* z   = (const float*)d_in[0];
    const float* emb = (const float*)d_in[1];
    const float* ecs = (const float*)d_in[2];
    const float* ees = (const float*)d_in[3];

    float* out = (float*)d_out;
    char*  ws  = (char*)d_ws;

    // ws head: enorm 32KB | key64 128KB | part_e 8KB | part_q 4KB | cnt 32KB
    //          | bucket 1MB
    float* enorm = (float*)ws;                                    // 8192 f
    unsigned long long* key64 = (unsigned long long*)(ws + 32768);// 16384 u64
    float* part_e = (float*)(ws + 163840);                        // 2048 f
    float* part_q = part_e + 2048;                                // 1024 f
    unsigned int* cnt = (unsigned int*)(ws + 176128);             // 8192 u32
    unsigned short* bucket = (unsigned short*)(ws + 208896);      // 8192*64 u16

    // bf16 hi/lo scratch: prefer d_ws if large enough, else alias output
    // regions overwritten later (zh/zl in O_QST, eh/el in O_EMB).
    const size_t big0 = 208896 + (size_t)KEMB * CAP * 2;          // 1257472
    const size_t bigbytes = (size_t)(NROWS + KEMB) * DDIM * 2 * 2;// 24 MB
    unsigned short *zh, *zl, *ehp, *elp;
    if (ws_size >= big0 + bigbytes) {
        zh  = (unsigned short*)(ws + big0);
        zl  = zh + NROWS * DDIM;
        ehp = zl + NROWS * DDIM;
        elp = ehp + KEMB * DDIM;
    } else {
        zh  = (unsigned short*)(out + O_QST);
        zl  = zh + NROWS * DDIM;
        ehp = (unsigned short*)(out + O_EMB);
        elp = ehp + KEMB * DDIM;
    }

    prep_all<<<6144, 256, 0, stream>>>(z, emb, ecs, ees, enorm, ehp, elp,
                                       zh, zl, out + O_EES, part_e, cnt, key64);
    argmin_mfma<<<dim3(NROWS / 256, KEMB / 256), 512, 0, stream>>>(zh, zl, ehp, elp, enorm, key64);
    quant_stats<<<NROWS / 16, 256, 0, stream>>>(z, emb, key64, out + O_QST, out + O_IDX,
                                                cnt, bucket, out + O_EES, part_q);
    finalize_kernel<<<KEMB, DDIM, 0, stream>>>(z, ecs, cnt, bucket,
                                               part_e, part_q,
                                               out + O_ECS, out + O_EES,
                                               out + O_EMB, out + O_LOSS);
}